// Round 8
// baseline (428.677 us; speedup 1.0000x reference)
//
#include <hip/hip_runtime.h>

typedef __attribute__((ext_vector_type(4))) float f32x4;
typedef __attribute__((ext_vector_type(2))) long i64x2;

// ---------- exact fp8 e4m3fn ENCODE (RNE, saturating), matching ml_dtypes ----------
__device__ __forceinline__ unsigned char enc_e4m3(float y) {
    unsigned int u = __float_as_uint(y);
    unsigned int s = (u >> 31) << 7;
    unsigned int a = u & 0x7fffffffu;
    if (a >= 0x3C800000u) {                       // |y| >= 2^-6: normal e4m3
        unsigned int r = a + 0x7FFFFu + ((a >> 20) & 1u);   // RNE to 3 mant bits
        r &= 0xFFF00000u;
        if (r > 0x43E00000u) r = 0x43E00000u;     // saturate 448
        unsigned int e = (r >> 23) - 120u;
        return (unsigned char)(s | (e << 3) | ((r >> 20) & 7u));
    } else {                                      // subnormal: grid 2^-9
        int m = (int)rintf(__uint_as_float(a) * 512.0f);
        return (unsigned char)(s | (unsigned)m);
    }
}

__device__ __forceinline__ unsigned short f32_to_bf16_bits(float f) {
    unsigned int u = __float_as_uint(f);
    u += 0x7FFFu + ((u >> 16) & 1u);
    return (unsigned short)(u >> 16);
}

// interleaved column within a 64-K block: chunk kh (16B) holds k={kh*8..+7} U {32+kh*8..+7}
__device__ __forceinline__ int ilv_col(int c) {   // c in [0,64)
    return ((c & 31) >> 3) * 16 + (c >> 5) * 8 + (c & 7);
}

// ---------- quantize x: per-row 1x64 tiles -> fp8 bytes (interleaved) + xsT[t][i] ----------
__global__ __launch_bounds__(256) void quant_x_kernel(const float* __restrict__ x,
                                                      unsigned char* __restrict__ xq,
                                                      float* __restrict__ xsT,
                                                      long long n4, int K, int M) {
    long long g = (long long)blockIdx.x * 256 + threadIdx.x;
    if (g >= n4) return;
    f32x4 v = ((const f32x4*)x)[g];
    float a = fmaxf(fmaxf(fabsf(v.x), fabsf(v.y)), fmaxf(fabsf(v.z), fabsf(v.w)));
    a = fmaxf(a, __shfl_xor(a, 1));
    a = fmaxf(a, __shfl_xor(a, 2));
    a = fmaxf(a, __shfl_xor(a, 4));
    a = fmaxf(a, __shfl_xor(a, 8));
    float scale = fmaxf(a, 1e-12f) / 448.0f;
    long long flat = g * 4;
    int row = (int)(flat / K);
    int rem = (int)(flat % K);
    int kb = rem >> 6, c0 = rem & 63;
    uchar4 o;
    o.x = enc_e4m3(v.x / scale);
    o.y = enc_e4m3(v.y / scale);
    o.z = enc_e4m3(v.z / scale);
    o.w = enc_e4m3(v.w / scale);
    *(uchar4*)(xq + (size_t)row * K + kb * 64 + ilv_col(c0)) = o;
    if ((c0 & 63) == 0)
        xsT[(size_t)kb * M + row] = scale;
}

// ---------- quantize w: 64x64 blocks -> fp8 (interleaved) + ws[nb][kb] ----------
__global__ __launch_bounds__(256) void quant_w_kernel(const float* __restrict__ w,
                                                      unsigned char* __restrict__ wq,
                                                      float* __restrict__ ws,
                                                      int N, int K) {
    const int nb = blockIdx.y, kb = blockIdx.x;
    const int KT = K >> 6;
    const int t = threadIdx.x;
    const int rgrp = t >> 4;
    const int cchk = t & 15;
    f32x4 v[4];
    float a = 0.0f;
#pragma unroll
    for (int i = 0; i < 4; ++i) {
        int row = nb * 64 + rgrp + i * 16;
        v[i] = *(const f32x4*)(w + (size_t)row * K + kb * 64 + cchk * 4);
        a = fmaxf(a, fmaxf(fmaxf(fabsf(v[i].x), fabsf(v[i].y)),
                           fmaxf(fabsf(v[i].z), fabsf(v[i].w))));
    }
#pragma unroll
    for (int off = 1; off < 64; off <<= 1) a = fmaxf(a, __shfl_xor(a, off));
    __shared__ float sm[4];
    if ((t & 63) == 0) sm[t >> 6] = a;
    __syncthreads();
    a = fmaxf(fmaxf(sm[0], sm[1]), fmaxf(sm[2], sm[3]));
    float scale = fmaxf(a, 1e-12f) / 448.0f;
    const int oc = ilv_col(cchk * 4);
#pragma unroll
    for (int i = 0; i < 4; ++i) {
        int row = nb * 64 + rgrp + i * 16;
        uchar4 o;
        o.x = enc_e4m3(v[i].x / scale);
        o.y = enc_e4m3(v[i].y / scale);
        o.z = enc_e4m3(v[i].z / scale);
        o.w = enc_e4m3(v[i].w / scale);
        *(uchar4*)(wq + (size_t)row * K + kb * 64 + oc) = o;
    }
    if (t == 0) ws[(size_t)nb * KT + kb] = scale;
}

// ---------- 256x256 block-scaled fp8 GEMM ----------
// kh-plane LDS layout (zero bank conflicts, R7-verified):
//   addr(row,kh) = kh*4096 + (row>>3)*128 + ((row&7)^kh)*16
// CL structure (R6-verified 39% MfmaUtil): p-chains and rescale fmacs in ONE
//   scheduling region per cluster; setprio only at cluster boundary so the
//   compiler interleaves the 8 independent chains (no MFMA-pipe drain).
#define GLDS(srcp, ldsp) __builtin_amdgcn_global_load_lds( \
    (__attribute__((address_space(1))) void*)(srcp),       \
    (__attribute__((address_space(3))) void*)(ldsp), 16, 0, 0)

#define MFMA8(aa, bb, cc) __builtin_amdgcn_mfma_f32_16x16x32_fp8_fp8(aa, bb, cc, 0, 0, 0)

__global__ __launch_bounds__(512, 2) void gemm_fp8(const unsigned char* __restrict__ Aq,
                                                   const unsigned char* __restrict__ Bq,
                                                   const float* __restrict__ xsT,
                                                   const float* __restrict__ wss,
                                                   const float* __restrict__ bias,
                                                   float* __restrict__ C,
                                                   int M, int N, int K) {
    __shared__ unsigned char Al[2][16384];
    __shared__ unsigned char Bl[2][16384];
    const int tid = threadIdx.x;
    const int wid = tid >> 6;
    const int lane = tid & 63;
    const int wm = wid >> 2, wn = wid & 3;
    const int l15 = lane & 15, kh = lane >> 4;
    const int KT = K >> 6, NT = KT;

    // XCD-aware bijective swizzle (nwg = 512, %8==0)
    const int nbx = N >> 8;
    const int nwg = (M >> 8) * nbx;
    const int bid = blockIdx.x;
    const int swz = (bid & 7) * (nwg >> 3) + (bid >> 3);
    const int tm = swz / nbx, tn = swz % nbx;

    const unsigned char* gA = Aq + (size_t)tm * 256 * K;
    const unsigned char* gB = Bq + (size_t)tn * 256 * K;

    const int iRow = tm * 256 + wm * 128 + l15;   // X-row base for scales/output
    const int jbw  = tn * 4 + wn;                 // W 64-block index

    // read-side base: kh-plane + swizzled slot + row-group
    const int rdswz = kh * 4096 + (((lane & 7) ^ kh) << 4);
    const unsigned char* pA_rd[2] = {
        &Al[0][0] + rdswz + (wm * 16 + (l15 >> 3)) * 128,
        &Al[1][0] + rdswz + (wm * 16 + (l15 >> 3)) * 128};
    const unsigned char* pB_rd[2] = {
        &Bl[0][0] + rdswz + (wn * 8 + (l15 >> 3)) * 128,
        &Bl[1][0] + rdswz + (wn * 8 + (l15 >> 3)) * 128};

    f32x4 macc[4][8];
#pragma unroll
    for (int n = 0; n < 4; ++n)
#pragma unroll
        for (int m = 0; m < 8; ++m) macc[n][m] = (f32x4){0.f, 0.f, 0.f, 0.f};

    i64x2 xf[8], wf[4];
    float xsA[8], xsB[8], wsA = 0.f, wsB = 0.f;
    float sarr[8];
    const f32x4 z4 = (f32x4){0.f, 0.f, 0.f, 0.f};

    // staging: linear LDS dest (chunk = i*64+lane); global row is the inverse swizzle
    auto STG = [&](int t, int bufn) {
#pragma unroll
        for (int j = 0; j < 2; ++j) {
            int i = wid * 2 + j;                   // 0..15
            int khs = i >> 2;                      // wave-uniform per GLDS
            int rowc = (i & 3) * 64 + ((lane >> 3) << 3) + ((lane & 7) ^ khs);
            size_t off = (size_t)rowc * K + (size_t)t * 64 + khs * 16;
            GLDS(gA + off, (char*)&Al[bufn][0] + i * 1024);
            GLDS(gB + off, (char*)&Bl[bufn][0] + i * 1024);
        }
    };

    // cluster: 8 independent p-chains, rescale fmacs in same sched region
    auto CL = [&](int mo, int no) {
#pragma unroll
        for (int mi = 0; mi < 4; ++mi) {
            const int m = mo + mi;
#pragma unroll
            for (int ni = 0; ni < 2; ++ni) {
                f32x4 p = MFMA8(wf[no + ni].x, xf[m].x, z4);
                p = MFMA8(wf[no + ni].y, xf[m].y, p);
                macc[no + ni][m] += p * sarr[m];
            }
        }
    };

    // prologue
    STG(0, 0);
#pragma unroll
    for (int m = 0; m < 8; ++m) xsA[m] = xsT[iRow + m * 16];
    wsA = wss[(size_t)jbw * KT];
    asm volatile("s_waitcnt vmcnt(0)" ::: "memory");
    asm volatile("s_barrier" ::: "memory");
#pragma unroll
    for (int m = 0; m < 4; ++m) xf[m] = *(const i64x2*)(pA_rd[0] + m * 256);
#pragma unroll
    for (int n = 0; n < 2; ++n) wf[n] = *(const i64x2*)(pB_rd[0] + n * 256);

    auto TILE = [&](int buf, int tnx, const float (&xsC)[8], float wsC,
                    float (&xsN)[8], float& wsN) {
        const unsigned char* pA = pA_rd[buf];
        const unsigned char* pB = pB_rd[buf];
        const unsigned char* pAn = pA_rd[buf ^ 1];
        const unsigned char* pBn = pB_rd[buf ^ 1];

#pragma unroll
        for (int m = 0; m < 8; ++m) sarr[m] = xsC[m] * wsC;   // 8 muls/tile

        // stage next tile + prefetch its scales
        STG(tnx, buf ^ 1);
#pragma unroll
        for (int m = 0; m < 8; ++m) xsN[m] = xsT[(size_t)tnx * M + iRow + m * 16];
        wsN = wss[(size_t)jbw * KT + tnx];

        // wf2-3, then clusters gated by counted lgkm
#pragma unroll
        for (int n = 0; n < 2; ++n) wf[n + 2] = *(const i64x2*)(pB + (n + 2) * 256);
        asm volatile("s_waitcnt lgkmcnt(2)" ::: "memory");
        __builtin_amdgcn_sched_barrier(0);
        __builtin_amdgcn_s_setprio(1);
        CL(0, 0);
        __builtin_amdgcn_s_setprio(0);

#pragma unroll
        for (int m = 0; m < 4; ++m) xf[m + 4] = *(const i64x2*)(pA + (m + 4) * 256);
        asm volatile("s_waitcnt lgkmcnt(4)" ::: "memory");
        __builtin_amdgcn_sched_barrier(0);
        __builtin_amdgcn_s_setprio(1);
        CL(0, 2);
        __builtin_amdgcn_s_setprio(0);

        asm volatile("s_waitcnt lgkmcnt(0)" ::: "memory");
        __builtin_amdgcn_sched_barrier(0);
        __builtin_amdgcn_s_setprio(1);
        CL(4, 2);
        CL(4, 0);
        __builtin_amdgcn_s_setprio(0);

        // tile boundary + tail-read next tile's first fragments
        asm volatile("s_waitcnt vmcnt(0)" ::: "memory");
        asm volatile("s_barrier" ::: "memory");
#pragma unroll
        for (int m = 0; m < 4; ++m) xf[m] = *(const i64x2*)(pAn + m * 256);
#pragma unroll
        for (int n = 0; n < 2; ++n) wf[n] = *(const i64x2*)(pBn + n * 256);
    };

    for (int t = 0; t < NT; t += 2) {
        int t1 = t + 1;
        int t2 = (t + 2 < NT) ? (t + 2) : 0;     // wrap: redundant but uniform
        TILE(0, t1, xsA, wsA, xsB, wsB);
        TILE(1, t2, xsB, wsB, xsA, wsA);
    }

    // epilogue: D col = lane&15 -> X-row; D rows -> W-cols (contiguous f32x4)
    const int jc0 = tn * 256 + wn * 64 + (lane >> 4) * 4;
#pragma unroll
    for (int ni = 0; ni < 4; ++ni) {
        f32x4 bv = *(const f32x4*)(bias + jc0 + ni * 16);
#pragma unroll
        for (int mi = 0; mi < 8; ++mi) {
            f32x4 vo;
#pragma unroll
            for (int j = 0; j < 4; ++j) {
                unsigned short b = f32_to_bf16_bits(macc[ni][mi][j]);
                vo[j] = __uint_as_float(((unsigned int)b) << 16) + bv[j];
            }
            *(f32x4*)(C + (size_t)(iRow + mi * 16) * N + jc0 + ni * 16) = vo;
        }
    }
}

extern "C" void kernel_launch(void* const* d_in, const int* in_sizes, int n_in,
                              void* d_out, int out_size, void* d_ws, size_t ws_size,
                              hipStream_t stream) {
    const float* x    = (const float*)d_in[0];
    const float* w    = (const float*)d_in[1];
    const float* bias = (const float*)d_in[2];
    float* out = (float*)d_out;

    const int N = in_sizes[2];
    const long long KL = (long long)in_sizes[1] / N;
    const int K = (int)KL;
    const int M = (int)((long long)in_sizes[0] / KL);
    const int KT = K / 64;

    unsigned char* xq = (unsigned char*)d_ws;                       // M*K fp8
    unsigned char* wq = xq + (size_t)M * K;                         // N*K fp8
    float* xsT = (float*)(wq + (size_t)N * K);                      // KT*M f32
    float* wss = xsT + (size_t)KT * M;                              // (N/64)*KT f32

    long long n4 = (long long)M * K / 4;
    quant_x_kernel<<<(unsigned)((n4 + 255) / 256), 256, 0, stream>>>(x, xq, xsT, n4, K, M);

    dim3 gw(K / 64, N / 64);
    quant_w_kernel<<<gw, 256, 0, stream>>>(w, wq, wss, N, K);

    const int nwg = (M / 256) * (N / 256);
    gemm_fp8<<<nwg, 512, 0, stream>>>(xq, wq, xsT, wss, bias, out, M, N, K);
}

// Round 9
// 334.374 us; speedup vs baseline: 1.2820x; 1.2820x over previous
//
#include <hip/hip_runtime.h>

typedef __attribute__((ext_vector_type(4))) float f32x4;
typedef __attribute__((ext_vector_type(2))) long i64x2;

// ---------- exact fp8 e4m3fn ENCODE (RNE, saturating), matching ml_dtypes ----------
__device__ __forceinline__ unsigned char enc_e4m3(float y) {
    unsigned int u = __float_as_uint(y);
    unsigned int s = (u >> 31) << 7;
    unsigned int a = u & 0x7fffffffu;
    if (a >= 0x3C800000u) {                       // |y| >= 2^-6: normal e4m3
        unsigned int r = a + 0x7FFFFu + ((a >> 20) & 1u);   // RNE to 3 mant bits
        r &= 0xFFF00000u;
        if (r > 0x43E00000u) r = 0x43E00000u;     // saturate 448
        unsigned int e = (r >> 23) - 120u;
        return (unsigned char)(s | (e << 3) | ((r >> 20) & 7u));
    } else {                                      // subnormal: grid 2^-9
        int m = (int)rintf(__uint_as_float(a) * 512.0f);
        return (unsigned char)(s | (unsigned)m);
    }
}

__device__ __forceinline__ unsigned short f32_to_bf16_bits(float f) {
    unsigned int u = __float_as_uint(f);
    u += 0x7FFFu + ((u >> 16) & 1u);
    return (unsigned short)(u >> 16);
}

// interleaved column within a 64-K block: chunk kh (16B) holds k={kh*8..+7} U {32+kh*8..+7}
__device__ __forceinline__ int ilv_col(int c) {   // c in [0,64)
    return ((c & 31) >> 3) * 16 + (c >> 5) * 8 + (c & 7);
}

// ---------- quantize x: per-row 1x64 tiles -> fp8 bytes (interleaved) + xsT[t][i] ----------
__global__ __launch_bounds__(256) void quant_x_kernel(const float* __restrict__ x,
                                                      unsigned char* __restrict__ xq,
                                                      float* __restrict__ xsT,
                                                      long long n4, int K, int M) {
    long long g = (long long)blockIdx.x * 256 + threadIdx.x;
    if (g >= n4) return;
    f32x4 v = ((const f32x4*)x)[g];
    float a = fmaxf(fmaxf(fabsf(v.x), fabsf(v.y)), fmaxf(fabsf(v.z), fabsf(v.w)));
    a = fmaxf(a, __shfl_xor(a, 1));
    a = fmaxf(a, __shfl_xor(a, 2));
    a = fmaxf(a, __shfl_xor(a, 4));
    a = fmaxf(a, __shfl_xor(a, 8));
    float scale = fmaxf(a, 1e-12f) / 448.0f;
    long long flat = g * 4;
    int row = (int)(flat / K);
    int rem = (int)(flat % K);
    int kb = rem >> 6, c0 = rem & 63;
    uchar4 o;
    o.x = enc_e4m3(v.x / scale);
    o.y = enc_e4m3(v.y / scale);
    o.z = enc_e4m3(v.z / scale);
    o.w = enc_e4m3(v.w / scale);
    *(uchar4*)(xq + (size_t)row * K + kb * 64 + ilv_col(c0)) = o;
    if ((c0 & 63) == 0)
        xsT[(size_t)kb * M + row] = scale;
}

// ---------- quantize w: 64x64 blocks -> fp8 (interleaved) + ws[nb][kb] ----------
__global__ __launch_bounds__(256) void quant_w_kernel(const float* __restrict__ w,
                                                      unsigned char* __restrict__ wq,
                                                      float* __restrict__ ws,
                                                      int N, int K) {
    const int nb = blockIdx.y, kb = blockIdx.x;
    const int KT = K >> 6;
    const int t = threadIdx.x;
    const int rgrp = t >> 4;
    const int cchk = t & 15;
    f32x4 v[4];
    float a = 0.0f;
#pragma unroll
    for (int i = 0; i < 4; ++i) {
        int row = nb * 64 + rgrp + i * 16;
        v[i] = *(const f32x4*)(w + (size_t)row * K + kb * 64 + cchk * 4);
        a = fmaxf(a, fmaxf(fmaxf(fabsf(v[i].x), fabsf(v[i].y)),
                           fmaxf(fabsf(v[i].z), fabsf(v[i].w))));
    }
#pragma unroll
    for (int off = 1; off < 64; off <<= 1) a = fmaxf(a, __shfl_xor(a, off));
    __shared__ float sm[4];
    if ((t & 63) == 0) sm[t >> 6] = a;
    __syncthreads();
    a = fmaxf(fmaxf(sm[0], sm[1]), fmaxf(sm[2], sm[3]));
    float scale = fmaxf(a, 1e-12f) / 448.0f;
    const int oc = ilv_col(cchk * 4);
#pragma unroll
    for (int i = 0; i < 4; ++i) {
        int row = nb * 64 + rgrp + i * 16;
        uchar4 o;
        o.x = enc_e4m3(v[i].x / scale);
        o.y = enc_e4m3(v[i].y / scale);
        o.z = enc_e4m3(v[i].z / scale);
        o.w = enc_e4m3(v[i].w / scale);
        *(uchar4*)(wq + (size_t)row * K + kb * 64 + oc) = o;
    }
    if (t == 0) ws[(size_t)nb * KT + kb] = scale;
}

// ---------- 256x256 block-scaled fp8 GEMM (R6 structure, fixed LDS swizzle) ----------
// LDS [256 rows][4 x 16B slots]; content chunk c of row r at slot q = c ^ f(r),
// f(r) = (r>>1)&3.  Intra-octet (parity,slot) pairs all distinct -> zero bank
// conflicts on b128 reads; staging quads still read 64B contiguous per row.
#define GLDS(srcp, ldsp) __builtin_amdgcn_global_load_lds( \
    (__attribute__((address_space(1))) void*)(srcp),       \
    (__attribute__((address_space(3))) void*)(ldsp), 16, 0, 0)

#define MFMA8(aa, bb, cc) __builtin_amdgcn_mfma_f32_16x16x32_fp8_fp8(aa, bb, cc, 0, 0, 0)

__global__ __launch_bounds__(512, 2) void gemm_fp8(const unsigned char* __restrict__ Aq,
                                                   const unsigned char* __restrict__ Bq,
                                                   const float* __restrict__ xsT,
                                                   const float* __restrict__ wss,
                                                   const float* __restrict__ bias,
                                                   float* __restrict__ C,
                                                   int M, int N, int K) {
    __shared__ unsigned char Al[2][16384];
    __shared__ unsigned char Bl[2][16384];
    const int tid = threadIdx.x;
    const int wid = tid >> 6;
    const int lane = tid & 63;
    const int wm = wid >> 2, wn = wid & 3;
    const int l15 = lane & 15;
    const int KT = K >> 6, NT = KT;

    // XCD-aware bijective swizzle (nwg = 512, %8==0)
    const int nbx = N >> 8;
    const int nwg = (M >> 8) * nbx;
    const int bid = blockIdx.x;
    const int swz = (bid & 7) * (nwg >> 3) + (bid >> 3);
    const int tm = swz / nbx, tn = swz % nbx;

    const unsigned char* gA = Aq + (size_t)tm * 256 * K;
    const unsigned char* gB = Bq + (size_t)tn * 256 * K;

    // staging source col swizzle: chunk = (lane&3) ^ ((lane>>3)&3)  [f(row)=(row>>1)&3]
    const int gswz = (((lane & 3) ^ ((lane >> 3) & 3)) << 4);
    // ds_read col swizzle: slot = kh ^ ((l15>>1)&3)
    const int cSwz = (((lane >> 4) ^ ((lane >> 1) & 3)) << 4);

    const int iRow = tm * 256 + wm * 128 + l15;   // X-row for scales/output
    const int jbw  = tn * 4 + wn;                 // W 64-block index

    f32x4 macc[4][8];                              // [nw][mx]
#pragma unroll
    for (int n = 0; n < 4; ++n)
#pragma unroll
        for (int m = 0; m < 8; ++m) macc[n][m] = (f32x4){0.f, 0.f, 0.f, 0.f};

    i64x2 xf[8], wf[4];
    float xsA[8], xsB[8], wsA = 0.f, wsB = 0.f;
    const f32x4 z4 = (f32x4){0.f, 0.f, 0.f, 0.f};

    auto STG = [&](int t, int bufn) {              // 4 GLDS/wave: full fp8 tiles
#pragma unroll
        for (int i = 0; i < 2; ++i) {
            int seg = wid * 2 + i;                 // 16 segs x 1KB (16 rows) per operand
            int row = seg * 16 + (lane >> 2);
            GLDS(gA + (size_t)row * K + (size_t)t * 64 + gswz, (char*)&Al[bufn][0] + seg * 1024);
            GLDS(gB + (size_t)row * K + (size_t)t * 64 + gswz, (char*)&Bl[bufn][0] + seg * 1024);
        }
    };

    const unsigned char* pAb[2] = {&Al[0][0] + (wm * 128 + l15) * 64 + cSwz,
                                   &Al[1][0] + (wm * 128 + l15) * 64 + cSwz};
    const unsigned char* pBb[2] = {&Bl[0][0] + (wn * 64 + l15) * 64 + cSwz,
                                   &Bl[1][0] + (wn * 64 + l15) * 64 + cSwz};

    // cluster: 4 mx x 2 nw fragments over K=64, then scale-FMA into macc
    auto CL = [&](int mo, int no, const float (&xs)[8], float wsv) {
#pragma unroll
        for (int mi = 0; mi < 4; ++mi) {
            float s = xs[mo + mi] * wsv;
#pragma unroll
            for (int ni = 0; ni < 2; ++ni) {
                f32x4 p = MFMA8(wf[no + ni].x, xf[mo + mi].x, z4);
                p = MFMA8(wf[no + ni].y, xf[mo + mi].y, p);
                macc[no + ni][mo + mi] += p * s;
            }
        }
    };

    // prologue: stage tile0 -> buf0, xs/ws for tile0
    STG(0, 0);
#pragma unroll
    for (int m = 0; m < 8; ++m) xsA[m] = xsT[iRow + m * 16];
    wsA = wss[(size_t)jbw * KT];
    asm volatile("s_waitcnt vmcnt(0)" ::: "memory");
    asm volatile("s_barrier" ::: "memory");
#pragma unroll
    for (int m = 0; m < 4; ++m) xf[m] = *(const i64x2*)(pAb[0] + m * 1024);
#pragma unroll
    for (int n = 0; n < 2; ++n) wf[n] = *(const i64x2*)(pBb[0] + n * 1024);

    auto TILE = [&](int buf, int tnx, const float (&xsC)[8], float wsC,
                    float (&xsN)[8], float& wsN) {
        const unsigned char* pA = pAb[buf];
        const unsigned char* pB = pBb[buf];
        const unsigned char* pAn = pAb[buf ^ 1];
        const unsigned char* pBn = pBb[buf ^ 1];

        // ph0: stage next tile + prefetch its scales; read wf2-3; c0
        STG(tnx, buf ^ 1);
#pragma unroll
        for (int m = 0; m < 8; ++m) xsN[m] = xsT[(size_t)tnx * M + iRow + m * 16];
        wsN = wss[(size_t)jbw * KT + tnx];
#pragma unroll
        for (int n = 0; n < 2; ++n) wf[n + 2] = *(const i64x2*)(pB + (n + 2) * 1024);
        asm volatile("s_waitcnt lgkmcnt(2)" ::: "memory");
        __builtin_amdgcn_sched_barrier(0);
        __builtin_amdgcn_s_setprio(1);
        CL(0, 0, xsC, wsC);
        __builtin_amdgcn_s_setprio(0);

        // ph1: read xf4-7; c1
#pragma unroll
        for (int m = 0; m < 4; ++m) xf[m + 4] = *(const i64x2*)(pA + (m + 4) * 1024);
        asm volatile("s_waitcnt lgkmcnt(4)" ::: "memory");
        __builtin_amdgcn_sched_barrier(0);
        __builtin_amdgcn_s_setprio(1);
        CL(0, 2, xsC, wsC);
        __builtin_amdgcn_s_setprio(0);

        // ph2: c2
        asm volatile("s_waitcnt lgkmcnt(0)" ::: "memory");
        __builtin_amdgcn_sched_barrier(0);
        __builtin_amdgcn_s_setprio(1);
        CL(4, 2, xsC, wsC);
        __builtin_amdgcn_s_setprio(0);

        // ph3: c3 (all frags live); then tile boundary + tail-read next c0
        __builtin_amdgcn_s_setprio(1);
        CL(4, 0, xsC, wsC);
        __builtin_amdgcn_s_setprio(0);
        asm volatile("s_waitcnt vmcnt(0)" ::: "memory");   // next buf fully staged
        asm volatile("s_barrier" ::: "memory");            // join all waves
#pragma unroll
        for (int m = 0; m < 4; ++m) xf[m] = *(const i64x2*)(pAn + m * 1024);
#pragma unroll
        for (int n = 0; n < 2; ++n) wf[n] = *(const i64x2*)(pBn + n * 1024);
    };

    for (int t = 0; t < NT; t += 2) {
        int t1 = t + 1;
        int t2 = (t + 2 < NT) ? (t + 2) : 0;     // wrap: redundant but uniform
        TILE(0, t1, xsA, wsA, xsB, wsB);
        TILE(1, t2, xsB, wsB, xsA, wsA);
    }

    // epilogue: D col = lane&15 -> X-row; D rows -> W-cols (contiguous f32x4)
    const int jc0 = tn * 256 + wn * 64 + (lane >> 4) * 4;
#pragma unroll
    for (int ni = 0; ni < 4; ++ni) {
        f32x4 bv = *(const f32x4*)(bias + jc0 + ni * 16);
#pragma unroll
        for (int mi = 0; mi < 8; ++mi) {
            f32x4 vo;
#pragma unroll
            for (int j = 0; j < 4; ++j) {
                unsigned short b = f32_to_bf16_bits(macc[ni][mi][j]);
                vo[j] = __uint_as_float(((unsigned int)b) << 16) + bv[j];
            }
            *(f32x4*)(C + (size_t)(iRow + mi * 16) * N + jc0 + ni * 16) = vo;
        }
    }
}

extern "C" void kernel_launch(void* const* d_in, const int* in_sizes, int n_in,
                              void* d_out, int out_size, void* d_ws, size_t ws_size,
                              hipStream_t stream) {
    const float* x    = (const float*)d_in[0];
    const float* w    = (const float*)d_in[1];
    const float* bias = (const float*)d_in[2];
    float* out = (float*)d_out;

    const int N = in_sizes[2];
    const long long KL = (long long)in_sizes[1] / N;
    const int K = (int)KL;
    const int M = (int)((long long)in_sizes[0] / KL);
    const int KT = K / 64;

    unsigned char* xq = (unsigned char*)d_ws;                       // M*K fp8
    unsigned char* wq = xq + (size_t)M * K;                         // N*K fp8
    float* xsT = (float*)(wq + (size_t)N * K);                      // KT*M f32
    float* wss = xsT + (size_t)KT * M;                              // (N/64)*KT f32

    long long n4 = (long long)M * K / 4;
    quant_x_kernel<<<(unsigned)((n4 + 255) / 256), 256, 0, stream>>>(x, xq, xsT, n4, K, M);

    dim3 gw(K / 64, N / 64);
    quant_w_kernel<<<gw, 256, 0, stream>>>(w, wq, wss, N, K);

    const int nwg = (M / 256) * (N / 256);
    gemm_fp8<<<nwg, 512, 0, stream>>>(xq, wq, xsT, wss, bias, out, M, N, K);
}